// Round 14
// baseline (105.595 us; speedup 1.0000x reference)
//
#include <hip/hip_runtime.h>

using u16 = unsigned short;
using u32 = unsigned int;
typedef __bf16 bf16x8 __attribute__((ext_vector_type(8)));
typedef u16 u16x8 __attribute__((ext_vector_type(8)));
typedef u16 u16x4 __attribute__((ext_vector_type(4)));
typedef u32 u32x2 __attribute__((ext_vector_type(2)));
typedef u32 u32x4 __attribute__((ext_vector_type(4)));
typedef float f32x4 __attribute__((ext_vector_type(4)));
typedef float f32x16 __attribute__((ext_vector_type(16)));

#define B_   2
#define S_   2048
#define DIN  1024
#define HID  1024
#define NH   16
#define NKV  4
#define HD_  64
#define QKVW 1536
// 0.125 * log2(e): folded into Q so softmax runs in exp2 domain
#define QSCL 0.1803368801111244f

__device__ __forceinline__ u16 f2b(float f) {
  u32 u = __builtin_bit_cast(u32, f);
  u32 r = (u + 0x7FFFu + ((u >> 16) & 1u)) >> 16;
  return (u16)r;
}

// async global->LDS, 16B per lane; dst = wave-uniform base + lane*16
__device__ __forceinline__ void gl16(const void* g, void* l) {
  __builtin_amdgcn_global_load_lds(
      (const __attribute__((address_space(1))) void*)g,
      (__attribute__((address_space(3))) void*)l, 16, 0, 0);
}

// ---------------- fused prep: x bf16-cast + all weight transposes ----------------
__global__ __launch_bounds__(256) void k_prep(
    const float* __restrict__ x, const float* __restrict__ Wq,
    const float* __restrict__ Wk, const float* __restrict__ Wv,
    const float* __restrict__ Wo,
    u16* __restrict__ xb, u16* __restrict__ WqkvT, u16* __restrict__ WoT)
{
  __shared__ float t[32][33];
  const int bid = blockIdx.x;
  if (bid < 2048) {
    const int i = bid * 256 + threadIdx.x;
    const float4* p = (const float4*)(x + (size_t)i * 8);
    float4 a = p[0], b = p[1];
    u16x8 o;
    o[0] = f2b(a.x); o[1] = f2b(a.y); o[2] = f2b(a.z); o[3] = f2b(a.w);
    o[4] = f2b(b.x); o[5] = f2b(b.y); o[6] = f2b(b.z); o[7] = f2b(b.w);
    *(u16x8*)(xb + (size_t)i * 8) = o;
    return;
  }
  const int wid = bid - 2048;
  const int k0 = (wid & 31) * 32;        // DIN/32 = 32 k-tiles
  const int n0 = (wid >> 5) * 32;        // 80 n-tiles: 48 qkv + 32 o
  const float* W; int N, nb, drow; u16* dst;
  if (n0 < HID)            { W = Wq; N = HID; nb = n0;              dst = WqkvT; drow = n0; }
  else if (n0 < HID + 256) { W = Wk; N = 256; nb = n0 - HID;        dst = WqkvT; drow = n0; }
  else if (n0 < QKVW)      { W = Wv; N = 256; nb = n0 - HID - 256;  dst = WqkvT; drow = n0; }
  else                     { W = Wo; N = HID; nb = n0 - QKVW;       dst = WoT;   drow = n0 - QKVW; }
  const int c = threadIdx.x & 31, r8 = threadIdx.x >> 5;
#pragma unroll
  for (int i = 0; i < 4; ++i)
    t[r8 + i * 8][c] = W[(size_t)(k0 + r8 + i * 8) * N + nb + c];
  __syncthreads();
#pragma unroll
  for (int i = 0; i < 4; ++i)
    dst[(size_t)(drow + r8 + i * 8) * DIN + k0 + c] = f2b(t[c][r8 + i * 8]);
}

// ---------------- GEMM: C = A * Bt^T (m97 128x128 tile, dbuf, gl16, XCD swizzle) ----------------
// 1D grid (gridDim.x % 8 == 0), gx = N/128 tiles per row. 4 waves in 2x2, each
// wave 64x64 out via 4x4 16x16x32 fragments: 8 ds_read_b128 feed 16 MFMA.
// If VtOut != null, output cols >= 1280 (the V projection) are written
// TRANSPOSED to VtOut[(b*256 + col-1280)][s] instead of C.
template <typename OutT>
__global__ __launch_bounds__(256, 2) void k_gemm_bt(
    const u16* __restrict__ A, const u16* __restrict__ Bt,
    OutT* __restrict__ C, int M, int N, int K, int scaleCols, float scl,
    int gx, u16* __restrict__ VtOut)
{
  __shared__ u16 lA[2][128 * 32];
  __shared__ u16 lB[2][128 * 32];
  // bijective XCD-chunk swizzle
  u32 wg = blockIdx.x;
  const u32 cpx = gridDim.x >> 3;
  wg = (wg & 7) * cpx + (wg >> 3);
  const int bm = (int)(wg / (u32)gx) * 128, bn = (int)(wg % (u32)gx) * 128;

  const int tid  = threadIdx.x;
  const int lane = tid & 63;
  const int wave = tid >> 6;
  const int wm = wave >> 1, wn = wave & 1;
  const int g = lane >> 4, li = lane & 15;
  const int srow = wave * 16 + (lane >> 2);    // + h*64
  const int scol = (lane & 3) * 8;

  f32x4 acc[4][4];
#pragma unroll
  for (int i = 0; i < 4; ++i)
#pragma unroll
    for (int j = 0; j < 4; ++j) acc[i][j] = f32x4{0.f, 0.f, 0.f, 0.f};

  const u16* Ab = A + (size_t)bm * K;
  const u16* Bb = Bt + (size_t)bn * K;

  auto stage = [&](int k0, int buf) {
#pragma unroll
    for (int h = 0; h < 2; ++h) {
      gl16(&Ab[(size_t)(h * 64 + srow) * K + k0 + scol], (char*)lA[buf] + h * 4096 + wave * 1024);
      gl16(&Bb[(size_t)(h * 64 + srow) * K + k0 + scol], (char*)lB[buf] + h * 4096 + wave * 1024);
    }
  };

  stage(0, 0);
  __syncthreads();

  int cur = 0;
  for (int k0 = 0; k0 < K; k0 += 32) {
    if (k0 + 32 < K) stage(k0 + 32, cur ^ 1);   // prefetch flies under MFMA
    bf16x8 af[4], bfr[4];
#pragma unroll
    for (int mt = 0; mt < 4; ++mt)
      af[mt] = *(const bf16x8*)&lA[cur][(wm * 64 + mt * 16 + li) * 32 + g * 8];
#pragma unroll
    for (int nt = 0; nt < 4; ++nt)
      bfr[nt] = *(const bf16x8*)&lB[cur][(wn * 64 + nt * 16 + li) * 32 + g * 8];
    __builtin_amdgcn_s_setprio(1);
#pragma unroll
    for (int mt = 0; mt < 4; ++mt)
#pragma unroll
      for (int nt = 0; nt < 4; ++nt)
        acc[mt][nt] = __builtin_amdgcn_mfma_f32_16x16x32_bf16(af[mt], bfr[nt], acc[mt][nt], 0, 0, 0);
    __builtin_amdgcn_s_setprio(0);
    __syncthreads();
    cur ^= 1;
  }

  const bool toVt = (VtOut != nullptr) && (bn + 128 > HID + 256);
  if (toVt) {
    // V-projection cols (>=1280) go transposed to VtOut; others normal.
    const int bofs = (bm >> 11) * 256;
#pragma unroll
    for (int mt = 0; mt < 4; ++mt) {
      const int sbase = (bm & (S_ - 1)) + wm * 64 + mt * 16 + g * 4;
#pragma unroll
      for (int nt = 0; nt < 4; ++nt) {
        const int col = bn + wn * 64 + nt * 16 + li;
        if (col >= HID + 256) {
          const int vtrow = bofs + col - (HID + 256);
          u16x4 pkv;
#pragma unroll
          for (int r = 0; r < 4; ++r) pkv[r] = f2b(acc[mt][nt][r]);
          *(u16x4*)&VtOut[(size_t)vtrow * S_ + sbase] = pkv;
        } else {
#pragma unroll
          for (int r = 0; r < 4; ++r) {
            int row = bm + wm * 64 + mt * 16 + g * 4 + r;
            C[(size_t)row * N + col] = (OutT)f2b(acc[mt][nt][r]);
          }
        }
      }
    }
  } else {
#pragma unroll
    for (int mt = 0; mt < 4; ++mt)
#pragma unroll
      for (int nt = 0; nt < 4; ++nt)
#pragma unroll
        for (int r = 0; r < 4; ++r) {
          int row = bm + wm * 64 + mt * 16 + g * 4 + r;
          int col = bn + wn * 64 + nt * 16 + li;
          float v = acc[mt][nt][r];
          if (col < scaleCols) v *= scl;
          if constexpr (sizeof(OutT) == 4) C[(size_t)row * N + col] = v;
          else                             C[(size_t)row * N + col] = f2b(v);
        }
  }
}

// ---------------- flash attention: cross-tile pipeline + XCD job remap (r13 incumbent) ----------------
__global__ __launch_bounds__(256, 2) void k_attn(
    const u16* __restrict__ QKV, const u16* __restrict__ Vt_g, u16* __restrict__ O)
{
  __shared__ u16 K_lds[3][64 * 64];
  __shared__ u16 Vt_lds[3][64 * 64];
  const int tid  = threadIdx.x;
  const int lane = tid & 63;
  const int w    = tid >> 6;       // head within kv group
  const int lq = lane & 31;        // query col / key row / d row
  const int hi = lane >> 5;
  const int swl = (lq & 7) << 3;
  const int hx = (hi * 8) ^ (swl & 8);
  // XCD-local job assignment (bijective over the 64x4x2 grid)
  const int g8 = blockIdx.x & 7;
  const int kv = g8 & 3;
  const int b  = g8 >> 2;
  const int s0 = (((int)blockIdx.z * 4 + (int)blockIdx.y) * 8 + ((int)blockIdx.x >> 3)) * 32;
  const int hq = kv * 4 + w;

  int dcol[4];
#pragma unroll
  for (int d0 = 0; d0 < 4; ++d0) dcol[d0] = (d0 * 16) ^ (swl & 48);

  // Q fragments (B-operand): Q[s0+lq][hq*64 + d0*16 + hi*8 ..+7]
  bf16x8 qf[4];
  {
    const u16* qb = QKV + (size_t)(b * S_ + s0 + lq) * QKVW + hq * HD_ + hi * 8;
#pragma unroll
    for (int d0 = 0; d0 < 4; ++d0) qf[d0] = *(const bf16x8*)(qb + d0 * 16);
  }

  float l = 0.f;
  f32x16 oacc0 = {}, oacc1 = {};
  bf16x8 pa[4];                    // P fragments of tile t-1 (live across iterations)

  // staging: wave w owns rows w*16..+15; LDS linear, global source pre-swizzled
  const int sr8 = lane >> 3;
  const int scol = ((lane & 7) ^ sr8) * 8;
  const int srow = w * 16;
  const u16* kge = QKV + (size_t)(b * S_) * QKVW + HID + kv * HD_;       // [key][d]
  const u16* vge = Vt_g + (size_t)((b * NKV + kv) * HD_) * S_;           // [d][key]

  auto stage = [&](int t, int buf) {
#pragma unroll
    for (int h = 0; h < 2; ++h) {
      gl16(kge + (size_t)(t * 64 + srow + h * 8 + sr8) * QKVW + scol,
           (char*)K_lds[buf] + srow * 128 + h * 1024);
      gl16(vge + (size_t)(srow + h * 8 + sr8) * S_ + t * 64 + scol,
           (char*)Vt_lds[buf] + srow * 128 + h * 1024);
    }
  };

  stage(0, 0);
  __syncthreads();

#define PK(dst, x, y) asm("v_cvt_pk_bf16_f32 %0, %1, %2" : "=v"(dst) : "v"(x), "v"(y))
  constexpr int NT = S_ / 64;
  int cb = 0;                      // t % 3
  for (int t = 0; t < NT; ++t) {
    int nb = cb + 1; if (nb == 3) nb = 0;     // (t+1)%3 : stage target
    int pb = cb - 1; if (pb < 0) pb = 2;      // (t-1)%3 : PV source
    if (t + 1 < NT) stage(t + 1, nb);

    // QK(t): S^T = K * Q^T (log2 units). st0 keys 0-31, st1 keys 32-63.
    f32x16 st0 = {}, st1 = {};
    const u16* Kc = K_lds[cb];
    __builtin_amdgcn_s_setprio(1);
#pragma unroll
    for (int d0 = 0; d0 < 4; ++d0) {
      bf16x8 kf0 = *(const bf16x8*)&Kc[lq * 64 + dcol[d0] + hx];
      bf16x8 kf1 = *(const bf16x8*)&Kc[(32 + lq) * 64 + dcol[d0] + hx];
      st0 = __builtin_amdgcn_mfma_f32_32x32x16_bf16(kf0, qf[d0], st0, 0, 0, 0);
      st1 = __builtin_amdgcn_mfma_f32_32x32x16_bf16(kf1, qf[d0], st1, 0, 0, 0);
    }

    // exp(t) in place + per-lane partial sum (scheduler mixes with PV below)
#pragma unroll
    for (int i = 0; i < 16; ++i) st0[i] = __builtin_amdgcn_exp2f(st0[i]);
#pragma unroll
    for (int i = 0; i < 16; ++i) st1[i] = __builtin_amdgcn_exp2f(st1[i]);
    float s8[8];
#pragma unroll
    for (int i = 0; i < 8; ++i)
      s8[i] = (st0[i] + st0[i + 8]) + (st1[i] + st1[i + 8]);
    s8[0] += s8[4]; s8[1] += s8[5]; s8[2] += s8[6]; s8[3] += s8[7];
    l += (s8[0] + s8[1]) + (s8[2] + s8[3]);

    // PV(t-1): O += P(32q x 64k) * V(64k x 64d)
    if (t > 0) {
      const u16* Vc = Vt_lds[pb];
#pragma unroll
      for (int ks = 0; ks < 4; ++ks) {
        bf16x8 vf0 = *(const bf16x8*)&Vc[lq * 64 + dcol[ks] + hx];
        bf16x8 vf1 = *(const bf16x8*)&Vc[(32 + lq) * 64 + dcol[ks] + hx];
        oacc0 = __builtin_amdgcn_mfma_f32_32x32x16_bf16(pa[ks], vf0, oacc0, 0, 0, 0);
        oacc1 = __builtin_amdgcn_mfma_f32_32x32x16_bf16(pa[ks], vf1, oacc1, 0, 0, 0);
      }
    }
    __builtin_amdgcn_s_setprio(0);

    // cvt(t) -> pa (consumed next iteration)
#pragma unroll
    for (int kb2 = 0; kb2 < 2; ++kb2) {
      const f32x16& ev = kb2 ? st1 : st0;
      u32 a0, a1, b0, b1;
      u32x2 r0, r1;
      u32x4 wv;
      PK(a0, ev[0], ev[1]);  PK(a1, ev[2], ev[3]);
      PK(b0, ev[4], ev[5]);  PK(b1, ev[6], ev[7]);
      r0 = __builtin_amdgcn_permlane32_swap(a0, b0, false, false);
      r1 = __builtin_amdgcn_permlane32_swap(a1, b1, false, false);
      wv[0] = r0[0]; wv[1] = r1[0]; wv[2] = r0[1]; wv[3] = r1[1];
      pa[kb2 * 2] = __builtin_bit_cast(bf16x8, wv);
      PK(a0, ev[8],  ev[9]);  PK(a1, ev[10], ev[11]);
      PK(b0, ev[12], ev[13]); PK(b1, ev[14], ev[15]);
      r0 = __builtin_amdgcn_permlane32_swap(a0, b0, false, false);
      r1 = __builtin_amdgcn_permlane32_swap(a1, b1, false, false);
      wv[0] = r0[0]; wv[1] = r1[0]; wv[2] = r0[1]; wv[3] = r1[1];
      pa[kb2 * 2 + 1] = __builtin_bit_cast(bf16x8, wv);
    }

    __syncthreads();   // readers of t-1 done; stage(t+1) drained
    cb = nb;
  }
#undef PK

  // drain: PV(NT-1)
  {
    int pb = cb - 1; if (pb < 0) pb = 2;
    const u16* Vc = Vt_lds[pb];
    __builtin_amdgcn_s_setprio(1);
#pragma unroll
    for (int ks = 0; ks < 4; ++ks) {
      bf16x8 vf0 = *(const bf16x8*)&Vc[lq * 64 + dcol[ks] + hx];
      bf16x8 vf1 = *(const bf16x8*)&Vc[(32 + lq) * 64 + dcol[ks] + hx];
      oacc0 = __builtin_amdgcn_mfma_f32_32x32x16_bf16(pa[ks], vf0, oacc0, 0, 0, 0);
      oacc1 = __builtin_amdgcn_mfma_f32_32x32x16_bf16(pa[ks], vf1, oacc1, 0, 0, 0);
    }
    __builtin_amdgcn_s_setprio(0);
  }

  // epilogue: one cross-half reduce for l, then O = oacc / l
  l += __shfl_xor(l, 32);
  const size_t obase = (size_t)(b * S_ + s0) * HID + hq * HD_ + lq;
#pragma unroll
  for (int r = 0; r < 16; ++r) {
    const int qrow = (r & 3) + 8 * (r >> 2) + 4 * hi;
    float lr = __shfl(l, qrow);
    float inv = __builtin_amdgcn_rcpf(lr);
    O[obase + (size_t)qrow * HID]      = f2b(oacc0[r] * inv);
    O[obase + (size_t)qrow * HID + 32] = f2b(oacc1[r] * inv);
  }
}

// ---------------- launch ----------------
extern "C" void kernel_launch(void* const* d_in, const int* in_sizes, int n_in,
                              void* d_out, int out_size, void* d_ws, size_t ws_size,
                              hipStream_t stream) {
  (void)in_sizes; (void)n_in; (void)out_size; (void)ws_size;
  const float* x  = (const float*)d_in[0];
  const float* Wq = (const float*)d_in[1];
  const float* Wk = (const float*)d_in[2];
  const float* Wv = (const float*)d_in[3];
  const float* Wo = (const float*)d_in[4];
  float* out = (float*)d_out;

  const size_t M = (size_t)B_ * S_;  // 4096
  u16* xb    = (u16*)d_ws;                        // M x 1024
  u16* WqkvT = xb    + M * DIN;                   // 1536 x 1024
  u16* WoT   = WqkvT + (size_t)QKVW * DIN;        // 1024 x 1024
  u16* QKV   = WoT   + (size_t)HID * HID;         // M x 1536 (V region unused)
  u16* Ob    = QKV   + M * QKVW;                  // M x 1024
  u16* Vt    = Ob    + M * HID;                   // (B*NKV*64) x 2048 = 2 MB

  // prep: x cast (2048 blocks) + weight transposes (2560 blocks)
  k_prep<<<dim3(4608), 256, 0, stream>>>(x, Wq, Wk, Wv, Wo, xb, WqkvT, WoT);

  // fused QKV projection; Q cols pre-scaled; V cols written transposed to Vt
  k_gemm_bt<u16><<<dim3(384), 256, 0, stream>>>(
      xb, WqkvT, QKV, (int)M, QKVW, DIN, HID, QSCL, QKVW / 128, Vt);

  k_attn<<<dim3(S_ / 32, NKV, B_), 256, 0, stream>>>(QKV, Vt, Ob);

  k_gemm_bt<float><<<dim3(256), 256, 0, stream>>>(
      Ob, WoT, out, (int)M, HID, HID, 0, 1.0f, HID / 128, nullptr);
}

// Round 16
// 99.222 us; speedup vs baseline: 1.0642x; 1.0642x over previous
//
#include <hip/hip_runtime.h>

using u16 = unsigned short;
using u32 = unsigned int;
typedef __bf16 bf16x8 __attribute__((ext_vector_type(8)));
typedef u16 u16x8 __attribute__((ext_vector_type(8)));
typedef u16 u16x4 __attribute__((ext_vector_type(4)));
typedef u32 u32x2 __attribute__((ext_vector_type(2)));
typedef u32 u32x4 __attribute__((ext_vector_type(4)));
typedef float f32x4 __attribute__((ext_vector_type(4)));
typedef float f32x16 __attribute__((ext_vector_type(16)));

#define B_   2
#define S_   2048
#define DIN  1024
#define HID  1024
#define NH   16
#define NKV  4
#define HD_  64
#define QKVW 1536
// 0.125 * log2(e): folded into Q so softmax runs in exp2 domain
#define QSCL 0.1803368801111244f

__device__ __forceinline__ u16 f2b(float f) {
  u32 u = __builtin_bit_cast(u32, f);
  u32 r = (u + 0x7FFFu + ((u >> 16) & 1u)) >> 16;
  return (u16)r;
}

// async global->LDS, 16B per lane; dst = wave-uniform base + lane*16
__device__ __forceinline__ void gl16(const void* g, void* l) {
  __builtin_amdgcn_global_load_lds(
      (const __attribute__((address_space(1))) void*)g,
      (__attribute__((address_space(3))) void*)l, 16, 0, 0);
}

// ---------------- fused prep: x bf16-cast + all weight transposes ----------------
__global__ __launch_bounds__(256) void k_prep(
    const float* __restrict__ x, const float* __restrict__ Wq,
    const float* __restrict__ Wk, const float* __restrict__ Wv,
    const float* __restrict__ Wo,
    u16* __restrict__ xb, u16* __restrict__ WqkvT, u16* __restrict__ WoT)
{
  __shared__ float t[32][33];
  const int bid = blockIdx.x;
  if (bid < 2048) {
    const int i = bid * 256 + threadIdx.x;
    const float4* p = (const float4*)(x + (size_t)i * 8);
    float4 a = p[0], b = p[1];
    u16x8 o;
    o[0] = f2b(a.x); o[1] = f2b(a.y); o[2] = f2b(a.z); o[3] = f2b(a.w);
    o[4] = f2b(b.x); o[5] = f2b(b.y); o[6] = f2b(b.z); o[7] = f2b(b.w);
    *(u16x8*)(xb + (size_t)i * 8) = o;
    return;
  }
  const int wid = bid - 2048;
  const int k0 = (wid & 31) * 32;        // DIN/32 = 32 k-tiles
  const int n0 = (wid >> 5) * 32;        // 80 n-tiles: 48 qkv + 32 o
  const float* W; int N, nb, drow; u16* dst;
  if (n0 < HID)            { W = Wq; N = HID; nb = n0;              dst = WqkvT; drow = n0; }
  else if (n0 < HID + 256) { W = Wk; N = 256; nb = n0 - HID;        dst = WqkvT; drow = n0; }
  else if (n0 < QKVW)      { W = Wv; N = 256; nb = n0 - HID - 256;  dst = WqkvT; drow = n0; }
  else                     { W = Wo; N = HID; nb = n0 - QKVW;       dst = WoT;   drow = n0 - QKVW; }
  const int c = threadIdx.x & 31, r8 = threadIdx.x >> 5;
#pragma unroll
  for (int i = 0; i < 4; ++i)
    t[r8 + i * 8][c] = W[(size_t)(k0 + r8 + i * 8) * N + nb + c];
  __syncthreads();
#pragma unroll
  for (int i = 0; i < 4; ++i)
    dst[(size_t)(drow + r8 + i * 8) * DIN + k0 + c] = f2b(t[c][r8 + i * 8]);
}

// ---------------- GEMM: C = A * Bt^T (128x64 tile, dbuf, gl16, XCD swizzle) ----------------
// K is compile-time (both GEMMs have K=1024): static trip count for the k-loop.
// 1D grid (gridDim.x % 8 == 0), gx = N/64 tiles per row. If VtOut != null,
// output cols >= 1280 (V projection) are written TRANSPOSED to
// VtOut[(b*256 + col-1280)][s] instead of C.
template <typename OutT, int K>
__global__ __launch_bounds__(256, 4) void k_gemm_bt(
    const u16* __restrict__ A, const u16* __restrict__ Bt,
    OutT* __restrict__ C, int M, int N, int scaleCols, float scl,
    int gx, u16* __restrict__ VtOut)
{
  __shared__ u16 lA[2][128 * 32];
  __shared__ u16 lB[2][64 * 32];
  // bijective XCD-chunk swizzle: blocks on one XCD (id%8) get contiguous tiles
  u32 wg = blockIdx.x;
  const u32 cpx = gridDim.x >> 3;
  wg = (wg & 7) * cpx + (wg >> 3);
  const int bm = (int)(wg / (u32)gx) * 128, bn = (int)(wg % (u32)gx) * 64;

  const int tid  = threadIdx.x;
  const int lane = tid & 63;
  const int wave = tid >> 6;
  const int wm = wave >> 1, wn = wave & 1;
  const int g = lane >> 4, li = lane & 15;
  const int arow = wave * 16 + (lane >> 2);
  const int acol = (lane & 3) * 8;

  f32x4 acc[4][2];
#pragma unroll
  for (int i = 0; i < 4; ++i)
#pragma unroll
    for (int j = 0; j < 2; ++j) acc[i][j] = f32x4{0.f, 0.f, 0.f, 0.f};

  const u16* Ab = A + (size_t)bm * K;
  const u16* Bb = Bt + (size_t)bn * K;

  auto stage = [&](int k0, int buf) {
#pragma unroll
    for (int h = 0; h < 2; ++h)
      gl16(&Ab[(size_t)(h * 64 + arow) * K + k0 + acol], (char*)lA[buf] + h * 4096 + wave * 1024);
    gl16(&Bb[(size_t)arow * K + k0 + acol], (char*)lB[buf] + wave * 1024);
  };

  stage(0, 0);
  __syncthreads();

  int cur = 0;
  for (int k0 = 0; k0 < K; k0 += 32) {
    if (k0 + 32 < K) stage(k0 + 32, cur ^ 1);   // prefetch flies under MFMA
    bf16x8 af[4], bfr[2];
#pragma unroll
    for (int mt = 0; mt < 4; ++mt)
      af[mt] = *(const bf16x8*)&lA[cur][(wm * 64 + mt * 16 + li) * 32 + g * 8];
#pragma unroll
    for (int nt = 0; nt < 2; ++nt)
      bfr[nt] = *(const bf16x8*)&lB[cur][(wn * 32 + nt * 16 + li) * 32 + g * 8];
    __builtin_amdgcn_s_setprio(1);
#pragma unroll
    for (int mt = 0; mt < 4; ++mt)
#pragma unroll
      for (int nt = 0; nt < 2; ++nt)
        acc[mt][nt] = __builtin_amdgcn_mfma_f32_16x16x32_bf16(af[mt], bfr[nt], acc[mt][nt], 0, 0, 0);
    __builtin_amdgcn_s_setprio(0);
    __syncthreads();
    cur ^= 1;
  }

  const bool toVt = (VtOut != nullptr) && (bn >= HID + 256);
  if (toVt) {
    // V projection block: write transposed; fragment rows are s-consecutive.
    const int bofs = (bm >> 11) * 256;
#pragma unroll
    for (int mt = 0; mt < 4; ++mt) {
      const int sbase = (bm & (S_ - 1)) + wm * 64 + mt * 16 + g * 4;
#pragma unroll
      for (int nt = 0; nt < 2; ++nt) {
        const int col = bn + wn * 32 + nt * 16 + li;
        const int vtrow = bofs + col - (HID + 256);
        u16x4 pkv;
#pragma unroll
        for (int r = 0; r < 4; ++r) pkv[r] = f2b(acc[mt][nt][r]);
        *(u16x4*)&VtOut[(size_t)vtrow * S_ + sbase] = pkv;
      }
    }
  } else {
#pragma unroll
    for (int mt = 0; mt < 4; ++mt)
#pragma unroll
      for (int nt = 0; nt < 2; ++nt)
#pragma unroll
        for (int r = 0; r < 4; ++r) {
          int row = bm + wm * 64 + mt * 16 + g * 4 + r;
          int col = bn + wn * 32 + nt * 16 + li;
          float v = acc[mt][nt][r];
          if (col < scaleCols) v *= scl;
          if constexpr (sizeof(OutT) == 4) C[(size_t)row * N + col] = v;
          else                             C[(size_t)row * N + col] = f2b(v);
        }
  }
}

// ---------------- flash attention: cross-tile pipeline + XCD job remap ----------------
// Swapped QK^T in exp2 domain, static-max softmax, P in registers via
// cvt_pk + permlane32_swap; iteration t runs QK(t) and PV(t-1) as one merged
// MFMA cluster; K/V LDS triple-buffered; gl16 with pre-swizzled global source.
// XCD remap: (kv,b) = blockIdx.x&7 -> each XCD holds ONE 512 KB K/V panel in L2.
__global__ __launch_bounds__(256, 2) void k_attn(
    const u16* __restrict__ QKV, const u16* __restrict__ Vt_g, u16* __restrict__ O)
{
  __shared__ u16 K_lds[3][64 * 64];
  __shared__ u16 Vt_lds[3][64 * 64];
  const int tid  = threadIdx.x;
  const int lane = tid & 63;
  const int w    = tid >> 6;       // head within kv group
  const int lq = lane & 31;        // query col / key row / d row
  const int hi = lane >> 5;
  const int swl = (lq & 7) << 3;
  const int hx = (hi * 8) ^ (swl & 8);
  // XCD-local job assignment (bijective over the 64x4x2 grid)
  const int g8 = blockIdx.x & 7;
  const int kv = g8 & 3;
  const int b  = g8 >> 2;
  const int s0 = (((int)blockIdx.z * 4 + (int)blockIdx.y) * 8 + ((int)blockIdx.x >> 3)) * 32;
  const int hq = kv * 4 + w;

  int dcol[4];
#pragma unroll
  for (int d0 = 0; d0 < 4; ++d0) dcol[d0] = (d0 * 16) ^ (swl & 48);

  // Q fragments (B-operand): Q[s0+lq][hq*64 + d0*16 + hi*8 ..+7]
  bf16x8 qf[4];
  {
    const u16* qb = QKV + (size_t)(b * S_ + s0 + lq) * QKVW + hq * HD_ + hi * 8;
#pragma unroll
    for (int d0 = 0; d0 < 4; ++d0) qf[d0] = *(const bf16x8*)(qb + d0 * 16);
  }

  float l = 0.f;
  f32x16 oacc0 = {}, oacc1 = {};
  bf16x8 pa[4];                    // P fragments of tile t-1 (live across iterations)

  // staging: wave w owns rows w*16..+15; LDS linear, global source pre-swizzled
  const int sr8 = lane >> 3;
  const int scol = ((lane & 7) ^ sr8) * 8;
  const int srow = w * 16;
  const u16* kge = QKV + (size_t)(b * S_) * QKVW + HID + kv * HD_;       // [key][d]
  const u16* vge = Vt_g + (size_t)((b * NKV + kv) * HD_) * S_;           // [d][key]

  auto stage = [&](int t, int buf) {
#pragma unroll
    for (int h = 0; h < 2; ++h) {
      gl16(kge + (size_t)(t * 64 + srow + h * 8 + sr8) * QKVW + scol,
           (char*)K_lds[buf] + srow * 128 + h * 1024);
      gl16(vge + (size_t)(srow + h * 8 + sr8) * S_ + t * 64 + scol,
           (char*)Vt_lds[buf] + srow * 128 + h * 1024);
    }
  };

  stage(0, 0);
  __syncthreads();

#define PK(dst, x, y) asm("v_cvt_pk_bf16_f32 %0, %1, %2" : "=v"(dst) : "v"(x), "v"(y))
  constexpr int NT = S_ / 64;
  int cb = 0;                      // t % 3
  for (int t = 0; t < NT; ++t) {
    int nb = cb + 1; if (nb == 3) nb = 0;     // (t+1)%3 : stage target
    int pb = cb - 1; if (pb < 0) pb = 2;      // (t-1)%3 : PV source
    if (t + 1 < NT) stage(t + 1, nb);

    // QK(t): S^T = K * Q^T (log2 units). st0 keys 0-31, st1 keys 32-63.
    f32x16 st0 = {}, st1 = {};
    const u16* Kc = K_lds[cb];
    __builtin_amdgcn_s_setprio(1);
#pragma unroll
    for (int d0 = 0; d0 < 4; ++d0) {
      bf16x8 kf0 = *(const bf16x8*)&Kc[lq * 64 + dcol[d0] + hx];
      bf16x8 kf1 = *(const bf16x8*)&Kc[(32 + lq) * 64 + dcol[d0] + hx];
      st0 = __builtin_amdgcn_mfma_f32_32x32x16_bf16(kf0, qf[d0], st0, 0, 0, 0);
      st1 = __builtin_amdgcn_mfma_f32_32x32x16_bf16(kf1, qf[d0], st1, 0, 0, 0);
    }

    // exp(t) in place + per-lane partial sum (scheduler mixes with PV below)
#pragma unroll
    for (int i = 0; i < 16; ++i) st0[i] = __builtin_amdgcn_exp2f(st0[i]);
#pragma unroll
    for (int i = 0; i < 16; ++i) st1[i] = __builtin_amdgcn_exp2f(st1[i]);
    float s8[8];
#pragma unroll
    for (int i = 0; i < 8; ++i)
      s8[i] = (st0[i] + st0[i + 8]) + (st1[i] + st1[i + 8]);
    s8[0] += s8[4]; s8[1] += s8[5]; s8[2] += s8[6]; s8[3] += s8[7];
    l += (s8[0] + s8[1]) + (s8[2] + s8[3]);

    // PV(t-1): O += P(32q x 64k) * V(64k x 64d)
    if (t > 0) {
      const u16* Vc = Vt_lds[pb];
#pragma unroll
      for (int ks = 0; ks < 4; ++ks) {
        bf16x8 vf0 = *(const bf16x8*)&Vc[lq * 64 + dcol[ks] + hx];
        bf16x8 vf1 = *(const bf16x8*)&Vc[(32 + lq) * 64 + dcol[ks] + hx];
        oacc0 = __builtin_amdgcn_mfma_f32_32x32x16_bf16(pa[ks], vf0, oacc0, 0, 0, 0);
        oacc1 = __builtin_amdgcn_mfma_f32_32x32x16_bf16(pa[ks], vf1, oacc1, 0, 0, 0);
      }
    }
    __builtin_amdgcn_s_setprio(0);

    // cvt(t) -> pa (consumed next iteration)
#pragma unroll
    for (int kb2 = 0; kb2 < 2; ++kb2) {
      const f32x16& ev = kb2 ? st1 : st0;
      u32 a0, a1, b0, b1;
      u32x2 r0, r1;
      u32x4 wv;
      PK(a0, ev[0], ev[1]);  PK(a1, ev[2], ev[3]);
      PK(b0, ev[4], ev[5]);  PK(b1, ev[6], ev[7]);
      r0 = __builtin_amdgcn_permlane32_swap(a0, b0, false, false);
      r1 = __builtin_amdgcn_permlane32_swap(a1, b1, false, false);
      wv[0] = r0[0]; wv[1] = r1[0]; wv[2] = r0[1]; wv[3] = r1[1];
      pa[kb2 * 2] = __builtin_bit_cast(bf16x8, wv);
      PK(a0, ev[8],  ev[9]);  PK(a1, ev[10], ev[11]);
      PK(b0, ev[12], ev[13]); PK(b1, ev[14], ev[15]);
      r0 = __builtin_amdgcn_permlane32_swap(a0, b0, false, false);
      r1 = __builtin_amdgcn_permlane32_swap(a1, b1, false, false);
      wv[0] = r0[0]; wv[1] = r1[0]; wv[2] = r0[1]; wv[3] = r1[1];
      pa[kb2 * 2 + 1] = __builtin_bit_cast(bf16x8, wv);
    }

    __syncthreads();   // readers of t-1 done; stage(t+1) drained
    cb = nb;
  }
#undef PK

  // drain: PV(NT-1)
  {
    int pb = cb - 1; if (pb < 0) pb = 2;
    const u16* Vc = Vt_lds[pb];
    __builtin_amdgcn_s_setprio(1);
#pragma unroll
    for (int ks = 0; ks < 4; ++ks) {
      bf16x8 vf0 = *(const bf16x8*)&Vc[lq * 64 + dcol[ks] + hx];
      bf16x8 vf1 = *(const bf16x8*)&Vc[(32 + lq) * 64 + dcol[ks] + hx];
      oacc0 = __builtin_amdgcn_mfma_f32_32x32x16_bf16(pa[ks], vf0, oacc0, 0, 0, 0);
      oacc1 = __builtin_amdgcn_mfma_f32_32x32x16_bf16(pa[ks], vf1, oacc1, 0, 0, 0);
    }
    __builtin_amdgcn_s_setprio(0);
  }

  // epilogue: one cross-half reduce for l, then O = oacc / l
  l += __shfl_xor(l, 32);
  const size_t obase = (size_t)(b * S_ + s0) * HID + hq * HD_ + lq;
#pragma unroll
  for (int r = 0; r < 16; ++r) {
    const int qrow = (r & 3) + 8 * (r >> 2) + 4 * hi;
    float lr = __shfl(l, qrow);
    float inv = __builtin_amdgcn_rcpf(lr);
    O[obase + (size_t)qrow * HID]      = f2b(oacc0[r] * inv);
    O[obase + (size_t)qrow * HID + 32] = f2b(oacc1[r] * inv);
  }
}

// ---------------- launch ----------------
extern "C" void kernel_launch(void* const* d_in, const int* in_sizes, int n_in,
                              void* d_out, int out_size, void* d_ws, size_t ws_size,
                              hipStream_t stream) {
  (void)in_sizes; (void)n_in; (void)out_size; (void)ws_size;
  const float* x  = (const float*)d_in[0];
  const float* Wq = (const float*)d_in[1];
  const float* Wk = (const float*)d_in[2];
  const float* Wv = (const float*)d_in[3];
  const float* Wo = (const float*)d_in[4];
  float* out = (float*)d_out;

  const size_t M = (size_t)B_ * S_;  // 4096
  u16* xb    = (u16*)d_ws;                        // M x 1024
  u16* WqkvT = xb    + M * DIN;                   // 1536 x 1024
  u16* WoT   = WqkvT + (size_t)QKVW * DIN;        // 1024 x 1024
  u16* QKV   = WoT   + (size_t)HID * HID;         // M x 1536 (V region unused)
  u16* Ob    = QKV   + M * QKVW;                  // M x 1024
  u16* Vt    = Ob    + M * HID;                   // (B*NKV*64) x 2048 = 2 MB

  // prep: x cast (2048 blocks) + weight transposes (2560 blocks)
  k_prep<<<dim3(4608), 256, 0, stream>>>(x, Wq, Wk, Wv, Wo, xb, WqkvT, WoT);

  // fused QKV projection; Q cols pre-scaled; V cols written transposed to Vt
  k_gemm_bt<u16, DIN><<<dim3(768), 256, 0, stream>>>(
      xb, WqkvT, QKV, (int)M, QKVW, HID, QSCL, QKVW / 64, Vt);

  k_attn<<<dim3(S_ / 32, NKV, B_), 256, 0, stream>>>(QKV, Vt, Ob);

  k_gemm_bt<float, HID><<<dim3(512), 256, 0, stream>>>(
      Ob, WoT, out, (int)M, HID, 0, 1.0f, HID / 64, nullptr);
}